// Round 1
// 507.875 us; speedup vs baseline: 1.0363x; 1.0363x over previous
//
#include <hip/hip_runtime.h>
#include <hip/hip_bf16.h>
#include <cstdint>

#define VOCAB 4096
#define ORDER 4
#define FAN   16388      // ORDER * (VOCAB + 1)
#define NL    2048
#define NPOS  16384      // B * L

typedef float        f4 __attribute__((ext_vector_type(4)));
typedef unsigned int u4 __attribute__((ext_vector_type(4)));
typedef unsigned int u2 __attribute__((ext_vector_type(2)));

static __device__ __forceinline__ unsigned short f2bf(float f)
{
    __hip_bfloat16 h = __float2bfloat16(f);
    unsigned short r;
    __builtin_memcpy(&r, &h, 2);
    return r;
}

// ---------------------------------------------------------------------------
// Pass 1: Wt[c][v] = bf16(W[v][c]).  128x128 tile via LDS (512 threads).
//   reads:  float4 nontemporal, 512-B contiguous chunks per row segment
//   writes: uint4 = 8 packed bf16, 256-B contiguous chunks per c-row
//   LDS: 128x129 f32 (66 KB) -> 2 blocks/CU. Conflicts <=4-way (non-critical).
// ---------------------------------------------------------------------------
__global__ __launch_bounds__(512) void k_transpose_bf16(
    const float* __restrict__ W, unsigned short* __restrict__ Wt)
{
    __shared__ float tile[128][129];          // [v][c], pad 129
    const int c0 = blockIdx.x * 128;          // fan_in tiles: 129
    const int v0 = blockIdx.y * 128;          // vocab tiles: 32

    // ---- load phase: thread reads float4 along c; wave = 512 B contiguous ----
    const int cq = (threadIdx.x & 31) * 4;    // 0..124
    const int vr = threadIdx.x >> 5;          // 0..15
    const bool cvalid = (c0 + cq) < FAN;      // FAN % 4 == 0 -> whole float4 valid

    #pragma unroll
    for (int i = 0; i < 8; ++i) {
        const int v = vr + 16 * i;
        if (cvalid) {
            const f4 f = __builtin_nontemporal_load(
                (const f4*)(W + (size_t)(v0 + v) * FAN + (c0 + cq)));
            tile[v][cq + 0] = f.x;
            tile[v][cq + 1] = f.y;
            tile[v][cq + 2] = f.z;
            tile[v][cq + 3] = f.w;
        }
    }
    __syncthreads();

    // ---- store phase: thread writes 8 consecutive v (packed bf16) per c ----
    const int p  = (threadIdx.x & 15) * 8;    // v offset 0..120
    const int cb = threadIdx.x >> 4;          // 0..31

    #pragma unroll
    for (int i = 0; i < 4; ++i) {
        const int cl = cb + 32 * i;           // 0..127
        const int c  = c0 + cl;
        if (c < FAN) {
            unsigned short s[8];
            #pragma unroll
            for (int j = 0; j < 8; ++j)
                s[j] = f2bf(tile[p + j][cl]);
            u4 pk;
            pk.x = (unsigned)s[0] | ((unsigned)s[1] << 16);
            pk.y = (unsigned)s[2] | ((unsigned)s[3] << 16);
            pk.z = (unsigned)s[4] | ((unsigned)s[5] << 16);
            pk.w = (unsigned)s[6] | ((unsigned)s[7] << 16);
            *(u4*)(Wt + (size_t)c * VOCAB + v0 + p) = pk;
        }
    }
}

// ---------------------------------------------------------------------------
// Pass 2: one block per TWO consecutive positions (same batch row: L is even).
//   - bias loaded once per thread per segment, reused for both positions
//   - 8 independent gather streams per segment (4 tables x 2 positions)
//   -每 store instruction is wave-contiguous: 64 lanes x float4 = 1 KB solid NT
// ---------------------------------------------------------------------------
__device__ __forceinline__ void accum4(float* acc, const u2& a)
{
    acc[0] += __uint_as_float(a.x << 16);
    acc[1] += __uint_as_float(a.x & 0xFFFF0000u);
    acc[2] += __uint_as_float(a.y << 16);
    acc[3] += __uint_as_float(a.y & 0xFFFF0000u);
}

__global__ __launch_bounds__(256) void k_gather(
    const int* __restrict__ idx, const unsigned short* __restrict__ Wt,
    const float* __restrict__ bias, float* __restrict__ out)
{
    const int pp = blockIdx.x * 2;            // even position
    const int bb = pp >> 11;                  // / NL
    const int l0 = pp & (NL - 1);             // even -> l0, l0+1 share batch row
    const int* row = idx + bb * NL;

    const unsigned short* r[2][ORDER];
    #pragma unroll
    for (int k = 0; k < ORDER; ++k) {
        const int s  = ORDER - 1 - k;
        const int t0 = (l0 >= s)     ? row[l0 - s]     : VOCAB;   // pad token
        const int t1 = (l0 + 1 >= s) ? row[l0 + 1 - s] : VOCAB;
        r[0][k] = Wt + (size_t)(k * (VOCAB + 1) + t0) * VOCAB;
        r[1][k] = Wt + (size_t)(k * (VOCAB + 1) + t1) * VOCAB;
    }

    float* o0 = out + (size_t)pp * VOCAB;
    float* o1 = o0 + VOCAB;
    const int j4 = threadIdx.x * 4;           // 4 consecutive v per thread

    #pragma unroll
    for (int seg = 0; seg < 4; ++seg) {
        const int v = seg * 1024 + j4;

        const f4 b = *(const f4*)(bias + v);
        float a0[4] = {b.x, b.y, b.z, b.w};
        float a1[4] = {b.x, b.y, b.z, b.w};

        #pragma unroll
        for (int k = 0; k < ORDER; ++k) {
            const u2 w0 = *(const u2*)(r[0][k] + v);
            const u2 w1 = *(const u2*)(r[1][k] + v);
            accum4(a0, w0);
            accum4(a1, w1);
        }

        f4 s0; s0.x = a0[0]; s0.y = a0[1]; s0.z = a0[2]; s0.w = a0[3];
        f4 s1; s1.x = a1[0]; s1.y = a1[1]; s1.z = a1[2]; s1.w = a1[3];
        __builtin_nontemporal_store(s0, (f4*)(o0 + v));
        __builtin_nontemporal_store(s1, (f4*)(o1 + v));
    }
}

// ---------------------------------------------------------------------------
// Fallback (ws too small): direct strided reads from W.  Correct, slower.
// ---------------------------------------------------------------------------
__global__ __launch_bounds__(256) void k_direct(
    const int* __restrict__ idx, const float* __restrict__ W,
    const float* __restrict__ bias, float* __restrict__ out)
{
    const int pos = blockIdx.x;
    const int bb  = pos >> 11;
    const int ll  = pos & (NL - 1);
    const int* row = idx + bb * NL;

    int off[ORDER];
    #pragma unroll
    for (int k = 0; k < ORDER; ++k) {
        const int s   = ORDER - 1 - k;
        const int tok = (ll >= s) ? row[ll - s] : VOCAB;
        off[k] = k * (VOCAB + 1) + tok;
    }

    float* o = out + (size_t)pos * VOCAB;
    for (int v = threadIdx.x; v < VOCAB; v += 256) {
        const float* wr = W + (size_t)v * FAN;
        o[v] = bias[v] + wr[off[0]] + wr[off[1]] + wr[off[2]] + wr[off[3]];
    }
}

// ---------------------------------------------------------------------------
extern "C" void kernel_launch(void* const* d_in, const int* in_sizes, int n_in,
                              void* d_out, int out_size, void* d_ws, size_t ws_size,
                              hipStream_t stream)
{
    const int*   idx  = (const int*)d_in[0];
    const float* W    = (const float*)d_in[1];
    const float* bias = (const float*)d_in[2];
    float*       out  = (float*)d_out;

    const size_t wt_bytes = (size_t)FAN * VOCAB * 2;   // 134.25 MB

    if (ws_size >= wt_bytes) {
        unsigned short* Wt = (unsigned short*)d_ws;
        dim3 g1((FAN + 127) / 128, VOCAB / 128);       // 129 x 32 tiles
        k_transpose_bf16<<<g1, 512, 0, stream>>>(W, Wt);
        k_gather<<<NPOS / 2, 256, 0, stream>>>(idx, Wt, bias, out);
    } else {
        k_direct<<<NPOS, 256, 0, stream>>>(idx, W, bias, out);
    }
}